// Round 6
// baseline (97.181 us; speedup 1.0000x reference)
//
#include <hip/hip_runtime.h>
#include <hip/hip_bf16.h>
#include <stdint.h>

#define Bn 8192
#define Dk 512

typedef __attribute__((ext_vector_type(8))) short short8;
typedef __attribute__((ext_vector_type(4))) float f32x4;

// fp32 -> bf16 bits, round-to-nearest-even
__device__ __forceinline__ unsigned short f2bf(float f) {
  unsigned int u = __float_as_uint(f);
  u += 0x7FFFu + ((u >> 16) & 1u);
  return (unsigned short)(u >> 16);
}

// async global -> LDS, 16 bytes per lane (dest = wave-uniform base + lane*16)
__device__ __forceinline__ void gload_lds16(const unsigned short* g, const short* l) {
  __builtin_amdgcn_global_load_lds(
      (const __attribute__((address_space(1))) void*)g,
      (__attribute__((address_space(3))) void*)l,
      16, 0, 0);
}

// ---------------------------------------------------------------------------
// Kernel 1: cast fp32 embeddings to bf16 (for MFMA) + exact fp32 row norms.
// ---------------------------------------------------------------------------
__global__ __launch_bounds__(256) void prep_kernel(
    const float* __restrict__ T, const float* __restrict__ M,
    unsigned short* __restrict__ Tb, unsigned short* __restrict__ Mb,
    float* __restrict__ tn, float* __restrict__ mn)
{
  const int bid = blockIdx.x;
  const int row = bid & (Bn - 1);
  const bool isM = bid >= Bn;
  const float* __restrict__ src = isM ? M : T;
  unsigned short* __restrict__ dst = isM ? Mb : Tb;
  const int tid = threadIdx.x;

  float2 v = reinterpret_cast<const float2*>(src + (size_t)row * Dk)[tid];
  float s = v.x * v.x + v.y * v.y;
  unsigned int packed = (unsigned int)f2bf(v.x) | ((unsigned int)f2bf(v.y) << 16);
  reinterpret_cast<unsigned int*>(dst + (size_t)row * Dk)[tid] = packed;

  #pragma unroll
  for (int off = 32; off >= 1; off >>= 1) s += __shfl_xor(s, off, 64);
  __shared__ float ws4[4];
  const int wave = tid >> 6, lane = tid & 63;
  if (lane == 0) ws4[wave] = s;
  __syncthreads();
  if (tid == 0) {
    float* nrm = isM ? mn : tn;
    nrm[row] = ws4[0] + ws4[1] + ws4[2] + ws4[3];
  }
}

// ---------------------------------------------------------------------------
// Kernel 2: 256x256-tile bf16 MFMA GEMM, BK=32, 4-deep LDS ring, prefetch
// depth 2, barrier every TWO K-steps (even steps, BEFORE the stage), NO
// explicit lgkmcnt drain (compiler emits counted lgkm per MFMA group so the
// read tail overlaps the MFMA head), counted vmcnt never 0 in steady state.
// Ring safety: overwrite of buf[kt-2] at step kt is preceded by the barrier
// at top of kt (even) or kt-1 (odd); every wave's reads of tile kt-2 are
// retired before its step-(kt-2) MFMA cluster ends, which precedes that
// barrier. vmcnt(8) after stage(kt+2) retires tile kt (in-order, m135).
// ---------------------------------------------------------------------------
__global__ __launch_bounds__(512, 2) void gemm_epi_kernel(
    const unsigned short* __restrict__ Tb, const unsigned short* __restrict__ Mb,
    const float* __restrict__ tn, const float* __restrict__ mn,
    const int* __restrict__ groups,
    float2* __restrict__ part)
{
  extern __shared__ char smem[];
  short* As = (short*)smem;                    // text tiles: 4 bufs x 256x32 bf16
  short* Bs = As + 4 * 8192;                   // image tiles: 4 bufs
  float2* tg_s = (float2*)(Bs + 4 * 8192);     // 256 (text norm, group bits)
  float2* mg_s = tg_s + 256;                   // 256 (image norm, group bits)

  const int tid = threadIdx.x;
  const int wave = tid >> 6;
  const int lane = tid & 63;
  const int llo = lane & 15, lhi = lane >> 4;

  // XCD-compact swizzle: 1024 blocks = 8 XCDs x (4 by x 32 bx), B-panel-major
  const int bid = blockIdx.x;
  const int xcd = bid & 7, lidx = bid >> 3;
  const int by = xcd * 4 + (lidx & 3);
  const int bx = lidx >> 2;
  const int brow = by * 256;   // text rows
  const int bcol = bx * 256;   // image rows

  const int ir = wave >> 2;    // image half: rows ir*128 .. +128
  const int tc = wave & 3;     // text quarter: cols tc*64 .. +64

  if (tid < 256) {
    tg_s[tid] = make_float2(tn[brow + tid], __uint_as_float((unsigned)groups[brow + tid]));
  } else {
    const int t = tid - 256;
    mg_s[t] = make_float2(mn[bcol + t], __uint_as_float((unsigned)groups[bcol + t]));
  }

  // staging geometry: K-tile = 256 rows x 32 bf16 = 1024 chunks of 16B;
  // 512 threads -> 2 issues per operand. Pre-swizzled global source (rule #21).
  int ldsoff[2];
  unsigned goffT[2], goffM[2];    // 32-bit element offsets (max 4M < 2^31)
  #pragma unroll
  for (int i = 0; i < 2; ++i) {
    const int c = i * 512 + tid;
    const int row = c >> 2;
    const int sc = (c & 3) ^ ((row >> 1) & 3);
    goffT[i] = (unsigned)(brow + row) * Dk + sc * 8;
    goffM[i] = (unsigned)(bcol + row) * Dk + sc * 8;
    ldsoff[i] = (i * 512 + wave * 64) * 8;     // wave-uniform chunk base (shorts)
  }

  auto stage = [&](int kt, int buf) {
    const int k0 = kt * 32;
    #pragma unroll
    for (int i = 0; i < 2; ++i) {
      gload_lds16(Tb + goffT[i] + k0, As + buf * 8192 + ldsoff[i]);
      gload_lds16(Mb + goffM[i] + k0, Bs + buf * 8192 + ldsoff[i]);
    }
  };

  // fragment read offsets (XOR-swizzled, kt-independent; row stride 32 shorts)
  int toff[4], moff[8];
  #pragma unroll
  for (int jt = 0; jt < 4; ++jt) {
    const int r = tc * 64 + jt * 16 + llo;
    toff[jt] = r * 32 + (lhi ^ ((r >> 1) & 3)) * 8;
  }
  #pragma unroll
  for (int it = 0; it < 8; ++it) {
    const int r = ir * 128 + it * 16 + llo;
    moff[it] = r * 32 + (lhi ^ ((r >> 1) & 3)) * 8;
  }

  f32x4 acc[8][4];
  #pragma unroll
  for (int it = 0; it < 8; ++it)
    #pragma unroll
    for (int jt = 0; jt < 4; ++jt)
      acc[it][jt] = f32x4{0.f, 0.f, 0.f, 0.f};

  stage(0, 0); stage(1, 1);
  int kt = 0;

#define STEP(BUF, DO_STAGE, DO_BAR, VMC)                                       \
  do {                                                                         \
    if (DO_BAR) __builtin_amdgcn_s_barrier();                                  \
    if (DO_STAGE) stage(kt + 2, ((BUF) + 2) & 3);                              \
    asm volatile("s_waitcnt vmcnt(" #VMC ")" ::: "memory");                    \
    short8 tf[4], mf[8];                                                       \
    _Pragma("unroll")                                                          \
    for (int jt = 0; jt < 4; ++jt)                                             \
      tf[jt] = *reinterpret_cast<const short8*>(&As[(BUF) * 8192 + toff[jt]]); \
    _Pragma("unroll")                                                          \
    for (int it = 0; it < 8; ++it)                                             \
      mf[it] = *reinterpret_cast<const short8*>(&Bs[(BUF) * 8192 + moff[it]]); \
    __builtin_amdgcn_s_setprio(1);                                             \
    _Pragma("unroll")                                                          \
    for (int it = 0; it < 8; ++it)                                             \
      _Pragma("unroll")                                                        \
      for (int jt = 0; jt < 4; ++jt)                                           \
        acc[it][jt] = __builtin_amdgcn_mfma_f32_16x16x32_bf16(                 \
            mf[it], tf[jt], acc[it][jt], 0, 0, 0);                             \
    __builtin_amdgcn_s_setprio(0);                                             \
    ++kt;                                                                      \
  } while (0)

  #pragma unroll 1
  for (int ko = 0; ko < 3; ++ko) {
    STEP(0, true, true,  8);
    STEP(1, true, false, 8);
    STEP(2, true, true,  8);
    STEP(3, true, false, 8);
  }
  STEP(0, true,  true,  8);   // kt=12: stages tile 14 -> buf 2
  STEP(1, true,  false, 8);   // kt=13: stages tile 15 -> buf 3 (last)
  STEP(2, false, true,  4);   // kt=14: tiles 14,15 outstanding -> wait to 4
  STEP(3, false, false, 0);   // kt=15: drain
#undef STEP

  // ---- fused epilogue (no atomics) ----
  // acc[it][jt][r] on lane (llo,lhi) = dot(image[bcol+ir*128+it*16+lhi*4+r],
  //                                        text [brow+tc*64+jt*16+llo])
  // red aliases As buf0 ONLY (16 KB): steps 14/15 read bufs 2/3, so the
  // barrier-free tail never touches buf0; __syncthreads before red reads.
  float2* red = reinterpret_cast<float2*>(As);   // 16 KB alias

  #pragma unroll
  for (int jt = 0; jt < 4; ++jt) {
    const int tl = tc * 64 + jt * 16 + llo;
    const float2 tg = tg_s[tl];
    const unsigned gt = __float_as_uint(tg.y);
    float nv = 0.f, dv = 0.f;
    #pragma unroll
    for (int it = 0; it < 8; ++it) {
      #pragma unroll
      for (int r = 0; r < 4; ++r) {
        const float2 mg = mg_s[ir * 128 + it * 16 + lhi * 4 + r];
        const float sq = fmaxf(tg.x + mg.x - 2.0f * acc[it][jt][r], 0.f);
        const float sim = __builtin_amdgcn_exp2f(-1.4426950408889634f *
                                                 __builtin_amdgcn_sqrtf(sq));
        if (gt == __float_as_uint(mg.y)) nv += sim; else dv += sim;
      }
    }
    red[(ir * 4 + lhi) * 256 + tl] = make_float2(nv, dv);
  }
  __syncthreads();
  if (tid < 256) {
    float nv = 0.f, dv = 0.f;
    #pragma unroll
    for (int s = 0; s < 8; ++s) {
      const float2 v = red[s * 256 + tid];
      nv += v.x; dv += v.y;
    }
    part[(size_t)bx * Bn + brow + tid] = make_float2(nv, dv);
  }
}

// ---------------------------------------------------------------------------
// Kernel 3a: per-row sum over 32 image-panel partials + loss term -> block sums.
// Kernel 3b: final reduce of 32 block sums.
// ---------------------------------------------------------------------------
__global__ __launch_bounds__(256) void finalize1_kernel(
    const float2* __restrict__ part, float* __restrict__ bsum)
{
  const int i = blockIdx.x * 256 + threadIdx.x;
  float nv = 0.f, dv = 0.f;
  #pragma unroll 8
  for (int p = 0; p < 32; ++p) {
    const float2 v = part[(size_t)p * Bn + i];
    nv += v.x; dv += v.y;
  }
  float li = (nv > 0.f && dv > 0.f)
      ? (__builtin_amdgcn_logf(dv) - __builtin_amdgcn_logf(nv)) * 0.69314718055994531f
      : 0.f;
  #pragma unroll
  for (int off = 32; off >= 1; off >>= 1) li += __shfl_xor(li, off, 64);
  __shared__ float ws4[4];
  if ((threadIdx.x & 63) == 0) ws4[threadIdx.x >> 6] = li;
  __syncthreads();
  if (threadIdx.x == 0) bsum[blockIdx.x] = ws4[0] + ws4[1] + ws4[2] + ws4[3];
}

__global__ void finalize2_kernel(const float* __restrict__ bsum, float* __restrict__ out)
{
  float s = (threadIdx.x < 32) ? bsum[threadIdx.x] : 0.f;
  #pragma unroll
  for (int off = 32; off >= 1; off >>= 1) s += __shfl_xor(s, off, 64);
  if (threadIdx.x == 0) out[0] = s / (float)Bn;
}

// ---------------------------------------------------------------------------
extern "C" void kernel_launch(void* const* d_in, const int* in_sizes, int n_in,
                              void* d_out, int out_size, void* d_ws, size_t ws_size,
                              hipStream_t stream) {
  const float* T = (const float*)d_in[0];
  const float* M = (const float*)d_in[1];
  const int* groups = (const int*)d_in[2];

  char* ws = (char*)d_ws;
  unsigned short* Tb = (unsigned short*)ws;                          // 8 MB
  unsigned short* Mb = (unsigned short*)(ws + (size_t)Bn * Dk * 2);  // 8 MB
  float* tn  = (float*)(ws + (size_t)Bn * Dk * 4);                   // 32 KB
  float* mn  = tn + Bn;                                              // 32 KB
  float2* part = (float2*)(mn + Bn);                                 // 2 MB (32 x 8192)
  float* bsum = (float*)(part + (size_t)32 * Bn);                    // 128 B

  const int smem_bytes = 4 * 8192 * 2 * 2 + 512 * 8;   // 128 KB tiles + 4 KB norms
  hipFuncSetAttribute((const void*)gemm_epi_kernel,
                      hipFuncAttributeMaxDynamicSharedMemorySize, smem_bytes);

  prep_kernel<<<2 * Bn, 256, 0, stream>>>(T, M, Tb, Mb, tn, mn);
  gemm_epi_kernel<<<1024, 512, smem_bytes, stream>>>(Tb, Mb, tn, mn, groups, part);
  finalize1_kernel<<<Bn / 256, 256, 0, stream>>>(part, bsum);
  finalize2_kernel<<<1, 64, 0, stream>>>(bsum, (float*)d_out);
}